// Round 3
// baseline (689.185 us; speedup 1.0000x reference)
//
#include <hip/hip_runtime.h>

// Painting: sequentially alpha-composite N RGBA layers onto a white canvas.
//   canvas = canvas*(1 - a) + a*poly,  a = poly[:,3]*0.8  (broadcast over RGBA)
// polys layout: (N, 1, 4, H, W) fp32 row-major. Output: (1, 4, H, W) fp32.
//
// Evidence so far: timed region = ~330us 2-GiB harness poison fill (fixed)
// + paint. Paint was ~333us at 1 wave/SIMD (R0): latency-bound, not BW-bound.
// Fix: block-local parallel scan over N. Each layer is an affine map
// c -> (1-a)*c + a*p; affine maps compose associatively. A block of 8 waves
// covers 64 float4 pixel-groups; wave w computes the affine (M, B) of
// N-chunk w in registers (every byte read exactly once), deposits 5 float4
// per thread into LDS (40 KiB), then 256 threads fold the 8 chunks in order.
// 8192 waves total (vs 1024 in R0), LDS caps 4 blocks/CU -> up to 32
// waves/CU streaming -> HBM-bound: 512 MiB / 6.3 TB/s ~= 85-120 us.

#define PH 512
#define PW 512
#define PHW (PH * PW)
#define PHW4 (PHW / 4)          // float4 groups per plane (65536)
#define OPACITY 0.8f
#define NCHUNK 8                // waves per block == N-chunks per pixel

__global__ __launch_bounds__(512) void paint_scan(const float4* __restrict__ polys,
                                                  float4* __restrict__ out,
                                                  int n_polys) {
    const int tid = threadIdx.x;
    const int w   = tid >> 6;                       // wave id = N-chunk id, 0..7
    const int l   = tid & 63;                       // lane
    const int group = blockIdx.x * 64 + l;          // pixel-group 0..PHW4-1

    // Chunk bounds (works for any n_polys; empty chunk -> identity map).
    const int n0 = (w * n_polys) / NCHUNK;
    const int n1 = ((w + 1) * n_polys) / NCHUNK;

    // Chunk affine: canvas_out = M * canvas_in + B  (M scalar-per-pixel, B RGBA)
    //   per layer: M *= (1-a);  B = B + a*(p - B)
    float4 m  = make_float4(1.f, 1.f, 1.f, 1.f);
    float4 b0 = make_float4(0.f, 0.f, 0.f, 0.f);
    float4 b1 = b0, b2 = b0, b3 = b0;

    const float4* p = polys + (size_t)n0 * 4 * PHW4 + group;
    #pragma unroll 2
    for (int n = n0; n < n1; ++n) {
        // 4 coalesced 1-KiB wave loads: R,G,B,A planes of layer n
        const float4 p0 = p[0 * PHW4];
        const float4 p1 = p[1 * PHW4];
        const float4 p2 = p[2 * PHW4];
        const float4 p3 = p[3 * PHW4];
        p += 4 * PHW4;

        const float ax = p3.x * OPACITY;
        const float ay = p3.y * OPACITY;
        const float az = p3.z * OPACITY;
        const float aw = p3.w * OPACITY;

        b0.x = fmaf(ax, p0.x - b0.x, b0.x);
        b0.y = fmaf(ay, p0.y - b0.y, b0.y);
        b0.z = fmaf(az, p0.z - b0.z, b0.z);
        b0.w = fmaf(aw, p0.w - b0.w, b0.w);

        b1.x = fmaf(ax, p1.x - b1.x, b1.x);
        b1.y = fmaf(ay, p1.y - b1.y, b1.y);
        b1.z = fmaf(az, p1.z - b1.z, b1.z);
        b1.w = fmaf(aw, p1.w - b1.w, b1.w);

        b2.x = fmaf(ax, p2.x - b2.x, b2.x);
        b2.y = fmaf(ay, p2.y - b2.y, b2.y);
        b2.z = fmaf(az, p2.z - b2.z, b2.z);
        b2.w = fmaf(aw, p2.w - b2.w, b2.w);

        b3.x = fmaf(ax, p3.x - b3.x, b3.x);
        b3.y = fmaf(ay, p3.y - b3.y, b3.y);
        b3.z = fmaf(az, p3.z - b3.z, b3.z);
        b3.w = fmaf(aw, p3.w - b3.w, b3.w);

        // m *= (1-a)  ==  m - a*m
        m.x = fmaf(-ax, m.x, m.x);
        m.y = fmaf(-ay, m.y, m.y);
        m.z = fmaf(-az, m.z, m.z);
        m.w = fmaf(-aw, m.w, m.w);
    }

    // Deposit chunk affine. Layout [chunk][plane][group]: lane-stride 16 B
    // -> 2-way bank aliasing only (free on CDNA4).
    __shared__ float4 lds[NCHUNK][5][64];
    lds[w][0][l] = m;
    lds[w][1][l] = b0;
    lds[w][2][l] = b1;
    lds[w][3][l] = b2;
    lds[w][4][l] = b3;
    __syncthreads();

    // Fold chunks in ascending order: c = M_k*c + B_k, c0 = 1 (white canvas).
    // 256 threads: one (channel, pixel-group) pair each.
    if (tid < 256) {
        const int g  = tid & 63;
        const int ch = tid >> 6;                    // 0..3
        float4 c = make_float4(1.f, 1.f, 1.f, 1.f);
        #pragma unroll
        for (int k = 0; k < NCHUNK; ++k) {
            const float4 mm = lds[k][0][g];
            const float4 bb = lds[k][1 + ch][g];
            c.x = fmaf(mm.x, c.x, bb.x);
            c.y = fmaf(mm.y, c.y, bb.y);
            c.z = fmaf(mm.z, c.z, bb.z);
            c.w = fmaf(mm.w, c.w, bb.w);
        }
        out[(size_t)ch * PHW4 + blockIdx.x * 64 + g] = c;
    }
}

extern "C" void kernel_launch(void* const* d_in, const int* in_sizes, int n_in,
                              void* d_out, int out_size, void* d_ws, size_t ws_size,
                              hipStream_t stream) {
    const float* polys = (const float*)d_in[0];
    float* out = (float*)d_out;

    // N derived from flat input element count; H=W=512 fixed by the reference.
    const int n_polys = in_sizes[0] / (4 * PHW);

    const int threads = 512;                 // 8 waves = 8 N-chunks
    const int blocks = PHW4 / 64;            // 1024 blocks x 64 pixel-groups
    paint_scan<<<blocks, threads, 0, stream>>>((const float4*)polys,
                                               (float4*)out, n_polys);
}